// Round 5
// baseline (64.240 us; speedup 1.0000x reference)
//
#include <hip/hip_runtime.h>

// RegionLoss v5: everything staged via async global_load_lds (zero-VGPR,
// guaranteed deep MLP), compute entirely from LDS.
// output: (nB, NA*32, nH, nW) f32 ; target: (nB, NA, nH, nW, 19) f32

namespace {

constexpr int kNC = 13;
constexpr int kCh = 32;                  // 19 + kNC channels per anchor
constexpr int kH = 76, kW = 76;
constexpr int kSP = kH * kW;             // 5776
constexpr int kCells = 32 * 5 * kSP;     // 924160
constexpr int kBlocks = kCells / 256;    // 3610 (exact)
constexpr int kTW = 256 * 19;            // 4864 target words per block

__device__ __forceinline__ void gl4(const float* g, float* l) {
  __builtin_amdgcn_global_load_lds(
      (const __attribute__((address_space(1))) void*)g,
      (__attribute__((address_space(3))) void*)l, 4, 0, 0);
}
__device__ __forceinline__ void gl16(const float* g, float* l) {
  __builtin_amdgcn_global_load_lds(
      (const __attribute__((address_space(1))) void*)g,
      (__attribute__((address_space(3))) void*)l, 16, 0, 0);
}

__global__ __launch_bounds__(256, 3)
void region_loss_v5(const float* __restrict__ out,
                    const float* __restrict__ tgt,
                    double* __restrict__ acc)
{
  __shared__ __align__(16) float ch[kCh][256];   // 32768 B
  __shared__ __align__(16) float tl[kTW];        // 19456 B
  __shared__ float wsum[4];

  const int tid  = threadIdx.x;
  const int blk  = blockIdx.x;
  const int lane = tid & 63;
  const int w    = tid >> 6;
  const int wbase = w * 64;                      // wave-uniform

  // per-lane cell -> per-lane global channel base (q handled per lane)
  const int n = blk * 256 + tid;
  const int q = n / kSP;                         // b*NA + a
  const int s = n - q * kSP;
  const float* op = out + (size_t)q * kCh * kSP + s;

  // ---- async stage: 32 channels, width 4 (lane = cell) ----
#pragma unroll
  for (int c = 0; c < kCh; ++c)
    gl4(op + (size_t)c * kSP, &ch[c][wbase]);

  // ---- async stage: target slab, width 16 x4 + width 4 x3 per wave ----
  const float* tg = tgt + (size_t)blk * kTW;     // block slab, 16B-aligned
#pragma unroll
  for (int k = 0; k < 4; ++k)
    gl16(tg + w * 1216 + k * 256 + lane * 4, &tl[w * 1216 + k * 256]);
#pragma unroll
  for (int r = 0; r < 3; ++r)
    gl4(tg + w * 1216 + 1024 + r * 64 + lane, &tl[w * 1216 + 1024 + r * 64]);

  __syncthreads();                               // drain vmcnt, barrier

  // ---- per-cell loss from LDS ----
  const int hh = s / kW;
  const float fh = (float)hh;
  const float fw = (float)(s - hh * kW);

  const int rb = tid * 19;
  const float clsf = tl[rb];
  const bool obj = (clsf != 0.f);

  float tcf = 0.f, lcd = 0.f;
#pragma unroll
  for (int i = 0; i < 9; ++i) {
    float xv = ch[14 + 2 * i][tid];
    float yv = ch[15 + 2 * i][tid];
    if (i == 0) {
      xv = __builtin_amdgcn_rcpf(1.f + __expf(-xv));
      yv = __builtin_amdgcn_rcpf(1.f + __expf(-yv));
    }
    const float gx = tl[rb + 1 + 2 * i];
    const float gy = tl[rb + 2 + 2 * i];
    const float tx = gx - fw;
    const float ty = gy - fh;
    const float dx = tx - (xv + fw);
    const float dy = ty - (yv + fh);
    const float dt = sqrtf(dx * dx + dy * dy);
    if (dt < 30.f) tcf += __expf(2.f - dt * (1.f / 15.f));
    const float ex = xv - tx;
    const float ey = yv - ty;
    lcd += ex * ex + ey * ey;
  }

  const float conf = ch[kNC][tid];
  const float d = conf - tcf * (1.f / 9.f);
  float loss = 0.005f * d * d;                   // 0.5*(0.1*(conf-tconf))^2
  if (obj) loss += 0.5f * lcd;

  if (obj) {
    float mx = ch[0][tid];
#pragma unroll
    for (int c = 1; c < kNC; ++c) mx = fmaxf(mx, ch[c][tid]);
    float se = 0.f;
#pragma unroll
    for (int c = 0; c < kNC; ++c) se += __expf(ch[c][tid] - mx);
    const int tc = (int)clsf;
    float sel = 0.f;
#pragma unroll
    for (int c = 0; c < kNC; ++c) sel += (c == tc) ? ch[c][tid] : 0.f;
    loss += -(sel - mx - __logf(se));
  }

  // ---- reduce: wave(64) shuffle -> LDS -> one double atomic per block ----
#pragma unroll
  for (int off = 32; off > 0; off >>= 1)
    loss += __shfl_down(loss, off, 64);

  if (lane == 0) wsum[w] = loss;
  __syncthreads();
  if (tid == 0)
    atomicAdd(acc, (double)(wsum[0] + wsum[1] + wsum[2] + wsum[3]));
}

__global__ void finalize_kernel(const double* __restrict__ acc,
                                float* __restrict__ outv)
{
  outv[0] = (float)acc[0];
}

}  // namespace

extern "C" void kernel_launch(void* const* d_in, const int* in_sizes, int n_in,
                              void* d_out, int out_size, void* d_ws, size_t ws_size,
                              hipStream_t stream) {
  const float* output = (const float*)d_in[0];
  const float* target = (const float*)d_in[1];
  double* acc = (double*)d_ws;

  hipMemsetAsync(acc, 0, sizeof(double), stream);

  region_loss_v5<<<kBlocks, 256, 0, stream>>>(output, target, acc);
  finalize_kernel<<<1, 1, 0, stream>>>(acc, (float*)d_out);
}